// Round 10
// baseline (1660.432 us; speedup 1.0000x reference)
//
#include <hip/hip_runtime.h>
#include <math.h>

#define BB 256
#define TT 2048
#define FF 2
#define HH 128
#define OO 2
#define NT 1024   // 16 waves = 4/SIMD; col j = tid>>3 (8 k-octant lanes/col)

typedef _Float16 h2 __attribute__((ext_vector_type(2)));

__device__ __forceinline__ float fast_rcp(float x) { return __builtin_amdgcn_rcpf(x); }
__device__ __forceinline__ float sigmoid_f(float x) { return fast_rcp(1.0f + __expf(-x)); }
__device__ __forceinline__ float tanh_f(float x) { return 1.0f - 2.0f * fast_rcp(1.0f + __expf(2.0f * x)); }

__device__ __forceinline__ float dot2(unsigned int hv, h2 w, float acc) {
#if __has_builtin(__builtin_amdgcn_fdot2)
    return __builtin_amdgcn_fdot2(__builtin_bit_cast(h2, hv), w, acc, false);
#else
    const h2 h = __builtin_bit_cast(h2, hv);
    acc = fmaf((float)h[0], (float)w[0], acc);
    return fmaf((float)h[1], (float)w[1], acc);
#endif
}

// 8 named h2 weights per gate (16 fp16 = this thread's k-octant slice)
#define DECL8(P)  h2 P##0, P##1, P##2, P##3, P##4, P##5, P##6, P##7;
#define LDP(P, i, BASE) \
    P##i[0] = (_Float16)BASE[(kb + 2*(i)    ) * HH]; \
    P##i[1] = (_Float16)BASE[(kb + 2*(i) + 1) * HH];
#define LOAD8(P, BASE) \
    LDP(P,0,BASE) LDP(P,1,BASE) LDP(P,2,BASE) LDP(P,3,BASE) \
    LDP(P,4,BASE) LDP(P,5,BASE) LDP(P,6,BASE) LDP(P,7,BASE)
#define DOT8(P, C0, C1, ACC) \
    ACC = dot2(C0.x, P##0, ACC); ACC = dot2(C0.y, P##1, ACC); \
    ACC = dot2(C0.z, P##2, ACC); ACC = dot2(C0.w, P##3, ACC); \
    ACC = dot2(C1.x, P##4, ACC); ACC = dot2(C1.y, P##5, ACC); \
    ACC = dot2(C1.z, P##6, ACC); ACC = dot2(C1.w, P##7, ACC);

__global__ __launch_bounds__(NT)
__attribute__((amdgpu_waves_per_eu(4, 4)))   // pin occupancy target: 16-wave
                                             // block = exactly 4 waves/SIMD,
                                             // VGPR budget 128 -> weights stay
                                             // resident (r9-proven mechanism)
void gru_persistent(const float* __restrict__ x, const float* __restrict__ h0,
                    const float* __restrict__ Wir, const float* __restrict__ Wiz,
                    const float* __restrict__ Win, const float* __restrict__ Whr,
                    const float* __restrict__ Whz, const float* __restrict__ Whn,
                    const float* __restrict__ bhr, const float* __restrict__ bhz,
                    const float* __restrict__ bhn, const float* __restrict__ Wd,
                    const float* __restrict__ bd, float* __restrict__ out)
{
    // out layout: [carry B*H][y B*T*O]
    __shared__ float x_sh[TT * FF];                    // 16 KB
    __shared__ __align__(16) float    h32[2][HH];      // fp32 master h, 2-buf
    __shared__ __align__(16) _Float16 h16[2][HH];      // fp16 copy, 2-buf

    const int b    = blockIdx.x;
    const int tid  = threadIdx.x;
    const int j    = tid >> 3;          // output column 0..127
    const int ks   = tid & 7;           // k-octant (16 h values)
    const int kb   = ks * 16;           // k base
    const int wv   = tid >> 6;
    const int lane = tid & 63;
    const bool lead = (ks == 0);

    // per-thread weight slices: 24 h2 VGPRs (3 gates x 16 k as half2)
    DECL8(wr) DECL8(wz) DECL8(wn)
    {
        const float* Wc;
        Wc = Whr + j; LOAD8(wr, Wc)
        Wc = Whz + j; LOAD8(wz, Wc)
        Wc = Whn + j; LOAD8(wn, Wc)
    }

    // leader extras (one lane per column)
    float br = 0.f, bz = 0.f, bn = 0.f;
    float wir0 = 0.f, wir1 = 0.f, wiz0 = 0.f, wiz1 = 0.f, win0 = 0.f, win1 = 0.f;
    if (lead) {
        br = bhr[j]; bz = bhz[j]; bn = bhn[j];
        wir0 = Wir[j]; wir1 = Wir[HH + j];
        wiz0 = Wiz[j]; wiz1 = Wiz[HH + j];
        win0 = Win[j]; win1 = Win[HH + j];
    }

    // wave 0 handles the tiny output projection y[t] = h @ Wd + bd
    float wdA0 = 0.f, wdA1 = 0.f, wdB0 = 0.f, wdB1 = 0.f, bd0 = 0.f, bd1 = 0.f;
    if (wv == 0) {
        wdA0 = Wd[lane * OO + 0];        wdA1 = Wd[lane * OO + 1];
        wdB0 = Wd[(lane + 64) * OO + 0]; wdB1 = Wd[(lane + 64) * OO + 1];
        bd0 = bd[0]; bd1 = bd[1];
    }

    // stage x row (exactly one float4 per thread) and h0 into buffer 0
    {
        const float4* xi = reinterpret_cast<const float4*>(x + (size_t)b * TT * FF);
        reinterpret_cast<float4*>(x_sh)[tid] = xi[tid];
    }
    if (tid < HH) {
        const float hv = h0[b * HH + tid];
        h32[0][tid] = hv;
        h16[0][tid] = (_Float16)hv;
    }
    __syncthreads();

    float* __restrict__ yout = out + BB * HH;

    for (int t = 0; t < TT; ++t) {
        const int bR = t & 1;            // h_state(t) lives here
        const int bW = bR ^ 1;           // h_state(t+1) goes here

        // this thread's 16-half slice of h(t): two uint4 broadcast chunks
        const uint4* hq = reinterpret_cast<const uint4*>(h16[bR]);
        const uint4 c0 = hq[ks * 2 + 0];
        const uint4 c1 = hq[ks * 2 + 1];

        float ra = 0.f, za = 0.f, ma = 0.f;
        DOT8(wr, c0, c1, ra)
        DOT8(wz, c0, c1, za)
        DOT8(wn, c0, c1, ma)

        // wave 0: emit y[t-1] = Wd . h_state(t) (reads bR, no hazard)
        if (wv == 0 && t > 0) {
            const float hv0 = h32[bR][lane], hv1 = h32[bR][lane + 64];
            float p0 = hv0 * wdA0 + hv1 * wdB0;
            float p1 = hv0 * wdA1 + hv1 * wdB1;
            #pragma unroll
            for (int off = 32; off >= 1; off >>= 1) {
                p0 += __shfl_xor(p0, off);
                p1 += __shfl_xor(p1, off);
            }
            if (lane == 0)
                reinterpret_cast<float2*>(yout)[(size_t)b * TT + (t - 1)] =
                    make_float2(p0 + bd0, p1 + bd1);
        }

        // in-wave 8-lane k-group reduction -> leader holds full dots
        #pragma unroll
        for (int m = 1; m <= 4; m <<= 1) {
            ra += __shfl_xor(ra, m);
            za += __shfl_xor(za, m);
            ma += __shfl_xor(ma, m);
        }

        if (lead) {
            const float hold = h32[bR][j];
            const float x0 = x_sh[t * FF + 0];
            const float x1 = x_sh[t * FF + 1];
            const float r  = sigmoid_f(ra + br + x0 * wir0 + x1 * wir1);
            const float z  = sigmoid_f(za + bz + x0 * wiz0 + x1 * wiz1);
            const float n  = tanh_f(x0 * win0 + x1 * win1 + r * (ma + bn));
            const float hn = (1.0f - z) * n + z * hold;
            h32[bW][j] = hn;
            h16[bW][j] = (_Float16)hn;
        }

        __syncthreads();   // SINGLE barrier: write(t) -> read(t+1)
    }

    // tail: y[T-1] = Wd . h_state(T); carry = h_state(T)  (buffer 0, T even)
    if (wv == 0) {
        const float hv0 = h32[0][lane], hv1 = h32[0][lane + 64];
        float p0 = hv0 * wdA0 + hv1 * wdB0;
        float p1 = hv0 * wdA1 + hv1 * wdB1;
        #pragma unroll
        for (int off = 32; off >= 1; off >>= 1) {
            p0 += __shfl_xor(p0, off);
            p1 += __shfl_xor(p1, off);
        }
        if (lane == 0)
            reinterpret_cast<float2*>(yout)[(size_t)b * TT + (TT - 1)] =
                make_float2(p0 + bd0, p1 + bd1);
    }
    if (tid < HH) out[b * HH + tid] = h32[0][tid];
}

extern "C" void kernel_launch(void* const* d_in, const int* in_sizes, int n_in,
                              void* d_out, int out_size, void* d_ws, size_t ws_size,
                              hipStream_t stream) {
    const float* x   = (const float*)d_in[0];
    const float* h0  = (const float*)d_in[1];
    const float* Wir = (const float*)d_in[2];
    const float* Wiz = (const float*)d_in[3];
    const float* Win = (const float*)d_in[4];
    const float* Whr = (const float*)d_in[5];
    const float* Whz = (const float*)d_in[6];
    const float* Whn = (const float*)d_in[7];
    const float* bhr = (const float*)d_in[8];
    const float* bhz = (const float*)d_in[9];
    const float* bhn = (const float*)d_in[10];
    const float* Wd  = (const float*)d_in[11];
    const float* bd  = (const float*)d_in[12];
    float* out = (float*)d_out;

    gru_persistent<<<BB, NT, 0, stream>>>(x, h0, Wir, Wiz, Win, Whr, Whz, Whn,
                                          bhr, bhz, bhn, Wd, bd, out);
}

// Round 11
// 1498.105 us; speedup vs baseline: 1.1084x; 1.1084x over previous
//
#include <hip/hip_runtime.h>
#include <math.h>

#define BB 256
#define TT 2048
#define FF 2
#define HH 128
#define OO 2
#define NT 256   // 4 waves = 1/SIMD; col j = tid>>1 (2 k-half lanes/col)

typedef _Float16 h2 __attribute__((ext_vector_type(2)));

__device__ __forceinline__ float fast_rcp(float x) { return __builtin_amdgcn_rcpf(x); }
__device__ __forceinline__ float sigmoid_f(float x) { return fast_rcp(1.0f + __expf(-x)); }
__device__ __forceinline__ float tanh_f(float x) { return 1.0f - 2.0f * fast_rcp(1.0f + __expf(2.0f * x)); }

__device__ __forceinline__ float dot2(unsigned int hv, h2 w, float acc) {
#if __has_builtin(__builtin_amdgcn_fdot2)
    return __builtin_amdgcn_fdot2(__builtin_bit_cast(h2, hv), w, acc, false);
#else
    const h2 h = __builtin_bit_cast(h2, hv);
    acc = fmaf((float)h[0], (float)w[0], acc);
    return fmaf((float)h[1], (float)w[1], acc);
#endif
}

// 32 named h2 weights per gate (64 fp16 = this thread's k-half slice)
#define FOR32(M, P) \
  M(P,0)  M(P,1)  M(P,2)  M(P,3)  M(P,4)  M(P,5)  M(P,6)  M(P,7)  \
  M(P,8)  M(P,9)  M(P,10) M(P,11) M(P,12) M(P,13) M(P,14) M(P,15) \
  M(P,16) M(P,17) M(P,18) M(P,19) M(P,20) M(P,21) M(P,22) M(P,23) \
  M(P,24) M(P,25) M(P,26) M(P,27) M(P,28) M(P,29) M(P,30) M(P,31)

#define DECLW(P,i) h2 P##i;
#define LOADW(P,i) P##i[0] = (_Float16)Wcol[(kb + 2*(i)    ) * HH]; \
                   P##i[1] = (_Float16)Wcol[(kb + 2*(i) + 1) * HH];

// one uint4 = 4 h2 of h -> 4 dot2 into one acc
#define DOTQ(P, Q, i0, i1, i2, i3, ACC)        \
    ACC = dot2(Q.x, P##i0, ACC);               \
    ACC = dot2(Q.y, P##i1, ACC);               \
    ACC = dot2(Q.z, P##i2, ACC);               \
    ACC = dot2(Q.w, P##i3, ACC);

__global__ __launch_bounds__(NT)
__attribute__((amdgpu_waves_per_eu(1, 1)))   // 4-wave block = exactly 1
                                             // wave/SIMD: full 512-VGPR
                                             // budget, no spill incentive
void gru_persistent(const float* __restrict__ x, const float* __restrict__ h0,
                    const float* __restrict__ Wir, const float* __restrict__ Wiz,
                    const float* __restrict__ Win, const float* __restrict__ Whr,
                    const float* __restrict__ Whz, const float* __restrict__ Whn,
                    const float* __restrict__ bhr, const float* __restrict__ bhz,
                    const float* __restrict__ bhn, const float* __restrict__ Wd,
                    const float* __restrict__ bd, float* __restrict__ out)
{
    // out layout: [carry B*H][y B*T*O]
    __shared__ float x_sh[TT * FF];                    // 16 KB
    __shared__ __align__(16) float    h32[2][HH];      // fp32 master h, 2-buf
    __shared__ __align__(16) _Float16 h16[2][HH];      // fp16 copy, 2-buf

    const int b    = blockIdx.x;
    const int tid  = threadIdx.x;
    const int j    = tid >> 1;          // output column 0..127
    const int ks   = tid & 1;           // k-half (64 h values)
    const int kb   = ks * 64;           // k base
    const int wv   = tid >> 6;
    const int lane = tid & 63;
    const bool lead = (ks == 0);

    // per-thread weight slices: 96 h2 VGPRs (3 gates x 32 h2)
    FOR32(DECLW, wr_) FOR32(DECLW, wz_) FOR32(DECLW, wn_)
    { const float* Wcol = Whr + j; FOR32(LOADW, wr_) }
    { const float* Wcol = Whz + j; FOR32(LOADW, wz_) }
    { const float* Wcol = Whn + j; FOR32(LOADW, wn_) }

    // leader extras (one lane per column)
    float br = 0.f, bz = 0.f, bn = 0.f;
    float wir0 = 0.f, wir1 = 0.f, wiz0 = 0.f, wiz1 = 0.f, win0 = 0.f, win1 = 0.f;
    if (lead) {
        br = bhr[j]; bz = bhz[j]; bn = bhn[j];
        wir0 = Wir[j]; wir1 = Wir[HH + j];
        wiz0 = Wiz[j]; wiz1 = Wiz[HH + j];
        win0 = Win[j]; win1 = Win[HH + j];
    }

    // wave 0 handles the tiny output projection y[t] = h @ Wd + bd
    float wdA0 = 0.f, wdA1 = 0.f, wdB0 = 0.f, wdB1 = 0.f, bd0 = 0.f, bd1 = 0.f;
    if (wv == 0) {
        wdA0 = Wd[lane * OO + 0];        wdA1 = Wd[lane * OO + 1];
        wdB0 = Wd[(lane + 64) * OO + 0]; wdB1 = Wd[(lane + 64) * OO + 1];
        bd0 = bd[0]; bd1 = bd[1];
    }

    // stage x row (4 float4 per thread) and h0 into buffer 0
    {
        const float4* xi = reinterpret_cast<const float4*>(x + (size_t)b * TT * FF);
        float4* xo = reinterpret_cast<float4*>(x_sh);
        #pragma unroll
        for (int i = 0; i < 4; ++i) xo[tid + i * NT] = xi[tid + i * NT];
    }
    if (tid < HH) {
        const float hv = h0[b * HH + tid];
        h32[0][tid] = hv;
        h16[0][tid] = (_Float16)hv;
    }
    __syncthreads();

    float* __restrict__ yout = out + BB * HH;

    for (int t = 0; t < TT; ++t) {
        const int bR = t & 1;            // h_state(t) lives here
        const int bW = bR ^ 1;           // h_state(t+1) goes here

        // this thread's 64-half slice of h(t): 8 uint4 broadcast chunks
        const uint4* hq = reinterpret_cast<const uint4*>(h16[bR]) + (ks << 3);
        const uint4 q0 = hq[0], q1 = hq[1], q2 = hq[2], q3 = hq[3];
        const uint4 q4 = hq[4], q5 = hq[5], q6 = hq[6], q7 = hq[7];

        // 96 dot2 in 6 independent 16-deep chains
        float r0 = 0.f, r1 = 0.f, z0 = 0.f, z1 = 0.f, m0 = 0.f, m1 = 0.f;
        DOTQ(wr_, q0,  0,  1,  2,  3, r0) DOTQ(wr_, q1,  4,  5,  6,  7, r0)
        DOTQ(wr_, q2,  8,  9, 10, 11, r0) DOTQ(wr_, q3, 12, 13, 14, 15, r0)
        DOTQ(wr_, q4, 16, 17, 18, 19, r1) DOTQ(wr_, q5, 20, 21, 22, 23, r1)
        DOTQ(wr_, q6, 24, 25, 26, 27, r1) DOTQ(wr_, q7, 28, 29, 30, 31, r1)
        DOTQ(wz_, q0,  0,  1,  2,  3, z0) DOTQ(wz_, q1,  4,  5,  6,  7, z0)
        DOTQ(wz_, q2,  8,  9, 10, 11, z0) DOTQ(wz_, q3, 12, 13, 14, 15, z0)
        DOTQ(wz_, q4, 16, 17, 18, 19, z1) DOTQ(wz_, q5, 20, 21, 22, 23, z1)
        DOTQ(wz_, q6, 24, 25, 26, 27, z1) DOTQ(wz_, q7, 28, 29, 30, 31, z1)
        DOTQ(wn_, q0,  0,  1,  2,  3, m0) DOTQ(wn_, q1,  4,  5,  6,  7, m0)
        DOTQ(wn_, q2,  8,  9, 10, 11, m0) DOTQ(wn_, q3, 12, 13, 14, 15, m0)
        DOTQ(wn_, q4, 16, 17, 18, 19, m1) DOTQ(wn_, q5, 20, 21, 22, 23, m1)
        DOTQ(wn_, q6, 24, 25, 26, 27, m1) DOTQ(wn_, q7, 28, 29, 30, 31, m1)

        // wave 0: emit y[t-1] = Wd . h_state(t) (reads bR, no hazard)
        if (wv == 0 && t > 0) {
            const float hv0 = h32[bR][lane], hv1 = h32[bR][lane + 64];
            float p0 = hv0 * wdA0 + hv1 * wdB0;
            float p1 = hv0 * wdA1 + hv1 * wdB1;
            #pragma unroll
            for (int off = 32; off >= 1; off >>= 1) {
                p0 += __shfl_xor(p0, off);
                p1 += __shfl_xor(p1, off);
            }
            if (lane == 0)
                reinterpret_cast<float2*>(yout)[(size_t)b * TT + (t - 1)] =
                    make_float2(p0 + bd0, p1 + bd1);
        }

        // pair reduction: one xor with the adjacent lane
        float ra = r0 + r1, za = z0 + z1, ma = m0 + m1;
        ra += __shfl_xor(ra, 1);
        za += __shfl_xor(za, 1);
        ma += __shfl_xor(ma, 1);

        if (lead) {
            const float hold = h32[bR][j];
            const float x0 = x_sh[t * FF + 0];
            const float x1 = x_sh[t * FF + 1];
            const float r  = sigmoid_f(ra + br + x0 * wir0 + x1 * wir1);
            const float z  = sigmoid_f(za + bz + x0 * wiz0 + x1 * wiz1);
            const float n  = tanh_f(x0 * win0 + x1 * win1 + r * (ma + bn));
            const float hn = (1.0f - z) * n + z * hold;
            h32[bW][j] = hn;
            h16[bW][j] = (_Float16)hn;
        }

        __syncthreads();   // single barrier: write(t) -> read(t+1)
    }

    // tail: y[T-1] = Wd . h_state(T); carry = h_state(T)  (buffer 0, T even)
    if (wv == 0) {
        const float hv0 = h32[0][lane], hv1 = h32[0][lane + 64];
        float p0 = hv0 * wdA0 + hv1 * wdB0;
        float p1 = hv0 * wdA1 + hv1 * wdB1;
        #pragma unroll
        for (int off = 32; off >= 1; off >>= 1) {
            p0 += __shfl_xor(p0, off);
            p1 += __shfl_xor(p1, off);
        }
        if (lane == 0)
            reinterpret_cast<float2*>(yout)[(size_t)b * TT + (TT - 1)] =
                make_float2(p0 + bd0, p1 + bd1);
    }
    if (tid < HH) out[b * HH + tid] = h32[0][tid];
}

extern "C" void kernel_launch(void* const* d_in, const int* in_sizes, int n_in,
                              void* d_out, int out_size, void* d_ws, size_t ws_size,
                              hipStream_t stream) {
    const float* x   = (const float*)d_in[0];
    const float* h0  = (const float*)d_in[1];
    const float* Wir = (const float*)d_in[2];
    const float* Wiz = (const float*)d_in[3];
    const float* Win = (const float*)d_in[4];
    const float* Whr = (const float*)d_in[5];
    const float* Whz = (const float*)d_in[6];
    const float* Whn = (const float*)d_in[7];
    const float* bhr = (const float*)d_in[8];
    const float* bhz = (const float*)d_in[9];
    const float* bhn = (const float*)d_in[10];
    const float* Wd  = (const float*)d_in[11];
    const float* bd  = (const float*)d_in[12];
    float* out = (float*)d_out;

    gru_persistent<<<BB, NT, 0, stream>>>(x, h0, Wir, Wiz, Win, Whr, Whz, Whn,
                                          bhr, bhz, bhn, Wd, bd, out);
}

// Round 12
// 1202.516 us; speedup vs baseline: 1.3808x; 1.2458x over previous
//
#include <hip/hip_runtime.h>
#include <math.h>

#define BB 256
#define TT 2048
#define FF 2
#define HH 128
#define OO 2
#define NT 256   // 4 waves = 1/SIMD; col j = tid>>1 (2 k-half lanes/col)

typedef _Float16 h2 __attribute__((ext_vector_type(2)));

__device__ __forceinline__ float fast_rcp(float x) { return __builtin_amdgcn_rcpf(x); }
__device__ __forceinline__ float sigmoid_f(float x) { return fast_rcp(1.0f + __expf(-x)); }
__device__ __forceinline__ float tanh_f(float x) { return 1.0f - 2.0f * fast_rcp(1.0f + __expf(2.0f * x)); }

__device__ __forceinline__ float dot2(unsigned int hv, h2 w, float acc) {
#if __has_builtin(__builtin_amdgcn_fdot2)
    return __builtin_amdgcn_fdot2(__builtin_bit_cast(h2, hv), w, acc, false);
#else
    const h2 h = __builtin_bit_cast(h2, hv);
    acc = fmaf((float)h[0], (float)w[0], acc);
    return fmaf((float)h[1], (float)w[1], acc);
#endif
}

// 32 named h2 weights per gate (64 fp16 = this thread's k-half slice)
#define FOR32(M, P) \
  M(P,0)  M(P,1)  M(P,2)  M(P,3)  M(P,4)  M(P,5)  M(P,6)  M(P,7)  \
  M(P,8)  M(P,9)  M(P,10) M(P,11) M(P,12) M(P,13) M(P,14) M(P,15) \
  M(P,16) M(P,17) M(P,18) M(P,19) M(P,20) M(P,21) M(P,22) M(P,23) \
  M(P,24) M(P,25) M(P,26) M(P,27) M(P,28) M(P,29) M(P,30) M(P,31)

#define DECLW(P,i) h2 P##i;
#define LOADW(P,i) P##i[0] = (_Float16)Wcol[(kb + 2*(i)    ) * HH]; \
                   P##i[1] = (_Float16)Wcol[(kb + 2*(i) + 1) * HH];

// one uint4 = 4 h2 of h -> 4 dot2 into one acc
#define DOTQ(P, Q, i0, i1, i2, i3, ACC)        \
    ACC = dot2(Q.x, P##i0, ACC);               \
    ACC = dot2(Q.y, P##i1, ACC);               \
    ACC = dot2(Q.z, P##i2, ACC);               \
    ACC = dot2(Q.w, P##i3, ACC);

__global__ __launch_bounds__(NT)
__attribute__((amdgpu_waves_per_eu(1, 1)))   // 1 wave/SIMD: full VGPR budget
void gru_persistent(const float* __restrict__ x, const float* __restrict__ h0,
                    const float* __restrict__ Wir, const float* __restrict__ Wiz,
                    const float* __restrict__ Win, const float* __restrict__ Whr,
                    const float* __restrict__ Whz, const float* __restrict__ Whn,
                    const float* __restrict__ bhr, const float* __restrict__ bhz,
                    const float* __restrict__ bhn, const float* __restrict__ Wd,
                    const float* __restrict__ bd, float* __restrict__ out)
{
    // out layout: [carry B*H][y B*T*O]
    __shared__ float x_sh[TT * FF];                      // 16 KB
    __shared__ __align__(16) _Float16 hist[64][HH];      // h ring, 16 KB

    const int b    = blockIdx.x;
    const int tid  = threadIdx.x;
    const int j    = tid >> 1;          // output column 0..127
    const int ks   = tid & 1;           // k-half (64 h values)
    const int kb   = ks * 64;           // k base
    const int wv   = tid >> 6;
    const int lane = tid & 63;
    const bool lead = (ks == 0);

    // per-thread weight slices: 96 h2 VGPRs (3 gates x 32 h2)
    FOR32(DECLW, wr_) FOR32(DECLW, wz_) FOR32(DECLW, wn_)
    { const float* Wcol = Whr + j; FOR32(LOADW, wr_) }
    { const float* Wcol = Whz + j; FOR32(LOADW, wz_) }
    { const float* Wcol = Whn + j; FOR32(LOADW, wn_) }

    // leader extras (one lane per column); hold = h_state(t)[j] in register
    float br = 0.f, bz = 0.f, bn = 0.f;
    float wir0 = 0.f, wir1 = 0.f, wiz0 = 0.f, wiz1 = 0.f, win0 = 0.f, win1 = 0.f;
    float hold = 0.f;
    if (lead) {
        br = bhr[j]; bz = bhz[j]; bn = bhn[j];
        wir0 = Wir[j]; wir1 = Wir[HH + j];
        wiz0 = Wiz[j]; wiz1 = Wiz[HH + j];
        win0 = Win[j]; win1 = Win[HH + j];
        hold = h0[b * HH + j];
    }

    // Wd columns for the deferred y flush (ALL threads)
    const float wdA0 = Wd[lane * OO + 0];
    const float wdA1 = Wd[lane * OO + 1];
    const float wdB0 = Wd[(lane + 64) * OO + 0];
    const float wdB1 = Wd[(lane + 64) * OO + 1];
    const float bd0 = bd[0], bd1 = bd[1];

    // stage x row (4 float4 per thread); h0 into ring slot 63
    {
        const float4* xi = reinterpret_cast<const float4*>(x + (size_t)b * TT * FF);
        float4* xo = reinterpret_cast<float4*>(x_sh);
        #pragma unroll
        for (int i = 0; i < 4; ++i) xo[tid + i * NT] = xi[tid + i * NT];
    }
    if (tid < HH) hist[63][tid] = (_Float16)h0[b * HH + tid];
    __syncthreads();

    float* __restrict__ yout = out + BB * HH;

    for (int t = 0; t < TT; ++t) {
        const int sR = (t + 63) & 63;    // slot holding h_state(t)

        // this thread's 64-half slice of h(t): 8 uint4 broadcast chunks
        const uint4* hq = reinterpret_cast<const uint4*>(hist[sR]) + (ks << 3);
        const uint4 q0 = hq[0], q1 = hq[1], q2 = hq[2], q3 = hq[3];
        const uint4 q4 = hq[4], q5 = hq[5], q6 = hq[6], q7 = hq[7];

        // 96 dot2 in 6 independent 16-deep chains
        float r0 = 0.f, r1 = 0.f, z0 = 0.f, z1 = 0.f, m0 = 0.f, m1 = 0.f;
        DOTQ(wr_, q0,  0,  1,  2,  3, r0) DOTQ(wr_, q1,  4,  5,  6,  7, r0)
        DOTQ(wr_, q2,  8,  9, 10, 11, r0) DOTQ(wr_, q3, 12, 13, 14, 15, r0)
        DOTQ(wr_, q4, 16, 17, 18, 19, r1) DOTQ(wr_, q5, 20, 21, 22, 23, r1)
        DOTQ(wr_, q6, 24, 25, 26, 27, r1) DOTQ(wr_, q7, 28, 29, 30, 31, r1)
        DOTQ(wz_, q0,  0,  1,  2,  3, z0) DOTQ(wz_, q1,  4,  5,  6,  7, z0)
        DOTQ(wz_, q2,  8,  9, 10, 11, z0) DOTQ(wz_, q3, 12, 13, 14, 15, z0)
        DOTQ(wz_, q4, 16, 17, 18, 19, z1) DOTQ(wz_, q5, 20, 21, 22, 23, z1)
        DOTQ(wz_, q6, 24, 25, 26, 27, z1) DOTQ(wz_, q7, 28, 29, 30, 31, z1)
        DOTQ(wn_, q0,  0,  1,  2,  3, m0) DOTQ(wn_, q1,  4,  5,  6,  7, m0)
        DOTQ(wn_, q2,  8,  9, 10, 11, m0) DOTQ(wn_, q3, 12, 13, 14, 15, m0)
        DOTQ(wn_, q4, 16, 17, 18, 19, m1) DOTQ(wn_, q5, 20, 21, 22, 23, m1)
        DOTQ(wn_, q6, 24, 25, 26, 27, m1) DOTQ(wn_, q7, 28, 29, 30, 31, m1)

        // pair reduction: one xor with the adjacent lane
        float ra = r0 + r1, za = z0 + z1, ma = m0 + m1;
        ra += __shfl_xor(ra, 1);
        za += __shfl_xor(za, 1);
        ma += __shfl_xor(ma, 1);

        if (lead) {
            const float x0 = x_sh[t * FF + 0];
            const float x1 = x_sh[t * FF + 1];
            const float r  = sigmoid_f(ra + br + x0 * wir0 + x1 * wir1);
            const float z  = sigmoid_f(za + bz + x0 * wiz0 + x1 * wiz1);
            const float n  = tanh_f(x0 * win0 + x1 * win1 + r * (ma + bn));
            const float hn = (1.0f - z) * n + z * hold;
            hold = hn;                        // register recurrence (fp32)
            hist[t & 63][j] = (_Float16)hn;   // ring write for next step + y
        }

        __syncthreads();   // single barrier: write(t) -> read(t+1)

        // deferred y flush: every 64 steps, 16 rows per wave
        if ((t & 63) == 63) {
            const int t0 = t - 63;
            #pragma unroll 4
            for (int i = 0; i < 16; ++i) {
                const int row = t0 + (wv << 4) + i;
                const int s   = row & 63;
                const float hv0 = (float)hist[s][lane];
                const float hv1 = (float)hist[s][lane + 64];
                float p0 = hv0 * wdA0 + hv1 * wdB0;
                float p1 = hv0 * wdA1 + hv1 * wdB1;
                #pragma unroll
                for (int off = 32; off >= 1; off >>= 1) {
                    p0 += __shfl_xor(p0, off);
                    p1 += __shfl_xor(p1, off);
                }
                if (lane == 0)
                    reinterpret_cast<float2*>(yout)[(size_t)b * TT + row] =
                        make_float2(p0 + bd0, p1 + bd1);
            }
            __syncthreads();   // flush reads done before slot reuse
        }
    }

    // carry = h_state(T) from lead registers (fp32)
    if (lead) out[b * HH + j] = hold;
}

extern "C" void kernel_launch(void* const* d_in, const int* in_sizes, int n_in,
                              void* d_out, int out_size, void* d_ws, size_t ws_size,
                              hipStream_t stream) {
    const float* x   = (const float*)d_in[0];
    const float* h0  = (const float*)d_in[1];
    const float* Wir = (const float*)d_in[2];
    const float* Wiz = (const float*)d_in[3];
    const float* Win = (const float*)d_in[4];
    const float* Whr = (const float*)d_in[5];
    const float* Whz = (const float*)d_in[6];
    const float* Whn = (const float*)d_in[7];
    const float* bhr = (const float*)d_in[8];
    const float* bhz = (const float*)d_in[9];
    const float* bhn = (const float*)d_in[10];
    const float* Wd  = (const float*)d_in[11];
    const float* bd  = (const float*)d_in[12];
    float* out = (float*)d_out;

    gru_persistent<<<BB, NT, 0, stream>>>(x, h0, Wir, Wiz, Win, Whr, Whz, Whn,
                                          bhr, bhz, bhn, Wd, bd, out);
}